// Round 15
// baseline (1378.803 us; speedup 1.0000x reference)
//
#include <hip/hip_runtime.h>
#include <hip/hip_bf16.h>
#include <math.h>

// GPT-2 small forward: B=2, S=1024, V=50257, D=768, H=12, L=6, F=3072, DK=64
#define BB 2
#define SS 1024
#define DD 768
#define HH 12
#define LL 6
#define FF 3072
#define VV 50257
#define DKK 64
#define NROWS (BB * SS)   // 2048
#define QKVN (3 * DD)     // 2304
#define QBLK 64
#define KVBLK 64
#define VPAD 50432        // 197*256 = logits N padded to 256-tile boundary

// Wt_all element layout per layer: [qkv 2304x768 | wo 768x768 | fc 3072x768 | proj 768x3072]
#define OFF_QKV 0
#define OFF_WO  1769472
#define OFF_FC  2359296
#define OFF_PROJ 4718592
#define PL      7077888   // elements per layer

typedef __attribute__((ext_vector_type(8))) short short8v;  // 8 bf16 = 4 VGPRs
typedef __attribute__((ext_vector_type(4))) float f32x4;
typedef __attribute__((ext_vector_type(4))) int int4v;

__device__ __forceinline__ float gelu_f(float x) {
    return 0.5f * x * (1.0f + erff(x * 0.70710678118654752440f));
}

// async 16B global->LDS DMA (dest = wave-uniform base + lane*16)
__device__ __forceinline__ void gload16(const void* g, void* l) {
    __builtin_amdgcn_global_load_lds(
        (const __attribute__((address_space(1))) void*)g,
        (__attribute__((address_space(3))) void*)l, 16, 0, 0);
}
// LDS byte offset of a __shared__ pointer (AS3 pointers are 32-bit)
__device__ __forceinline__ unsigned lds_off(const void* p) {
    return (unsigned)(size_t)(const __attribute__((address_space(3))) char*)p;
}
// raw ds_read_b128 — opaque to the waitcnt pass (counted-lgkmcnt discipline)
__device__ __forceinline__ short8v ds_read128(unsigned addr) {
    short8v r;
    asm volatile("ds_read_b128 %0, %1" : "=v"(r) : "v"(addr));
    return r;
}

// ---------------- embedding ----------------
__global__ __launch_bounds__(256) void embed_kernel(
    const int* __restrict__ ids, const float* __restrict__ tok,
    const float* __restrict__ pos, float* __restrict__ x) {
    int row = blockIdx.x;
    int s = row & (SS - 1);
    int id = ids[row];
    const float* t = tok + (size_t)id * DD;
    const float* p = pos + (size_t)s * DD;
    float* xr = x + (size_t)row * DD;
    for (int i = threadIdx.x; i < DD; i += 256)
        xr[i] = t[i] + p[i];
}

// ---------------- layernorm (fp32 in, fp32 out) — fallback ----------------
__global__ __launch_bounds__(256) void ln_kernel(
    const float* __restrict__ x, const float* __restrict__ g,
    const float* __restrict__ b, float* __restrict__ out) {
    int row = blockIdx.x;
    int tid = threadIdx.x;
    const float* xr = x + (size_t)row * DD;
    float v0 = xr[tid], v1 = xr[tid + 256], v2 = xr[tid + 512];
    __shared__ float red[256];
    red[tid] = v0 + v1 + v2;
    __syncthreads();
    for (int s2 = 128; s2 > 0; s2 >>= 1) {
        if (tid < s2) red[tid] += red[tid + s2];
        __syncthreads();
    }
    float mu = red[0] * (1.0f / DD);
    __syncthreads();
    float d0 = v0 - mu, d1 = v1 - mu, d2 = v2 - mu;
    red[tid] = d0 * d0 + d1 * d1 + d2 * d2;
    __syncthreads();
    for (int s2 = 128; s2 > 0; s2 >>= 1) {
        if (tid < s2) red[tid] += red[tid + s2];
        __syncthreads();
    }
    float r = rsqrtf(red[0] * (1.0f / DD) + 1e-5f);
    float* o = out + (size_t)row * DD;
    o[tid]       = d0 * r * g[tid]       + b[tid];
    o[tid + 256] = d1 * r * g[tid + 256] + b[tid + 256];
    o[tid + 512] = d2 * r * g[tid + 512] + b[tid + 512];
}

// ---------------- layernorm (fp32 in, bf16 out) ----------------
__global__ __launch_bounds__(256) void ln_bf16_kernel(
    const float* __restrict__ x, const float* __restrict__ g,
    const float* __restrict__ b, __hip_bfloat16* __restrict__ out) {
    int row = blockIdx.x;
    int tid = threadIdx.x;
    const float* xr = x + (size_t)row * DD;
    float v0 = xr[tid], v1 = xr[tid + 256], v2 = xr[tid + 512];
    __shared__ float red[256];
    red[tid] = v0 + v1 + v2;
    __syncthreads();
    for (int s2 = 128; s2 > 0; s2 >>= 1) {
        if (tid < s2) red[tid] += red[tid + s2];
        __syncthreads();
    }
    float mu = red[0] * (1.0f / DD);
    __syncthreads();
    float d0 = v0 - mu, d1 = v1 - mu, d2 = v2 - mu;
    red[tid] = d0 * d0 + d1 * d1 + d2 * d2;
    __syncthreads();
    for (int s2 = 128; s2 > 0; s2 >>= 1) {
        if (tid < s2) red[tid] += red[tid + s2];
        __syncthreads();
    }
    float r = rsqrtf(red[0] * (1.0f / DD) + 1e-5f);
    __hip_bfloat16* o = out + (size_t)row * DD;
    o[tid]       = __float2bfloat16(d0 * r * g[tid]       + b[tid]);
    o[tid + 256] = __float2bfloat16(d1 * r * g[tid + 256] + b[tid + 256]);
    o[tid + 512] = __float2bfloat16(d2 * r * g[tid + 512] + b[tid + 512]);
}

// ---------------- single W [K,N] f32 -> Wt [N,K] bf16 (mid path) ----------------
__global__ __launch_bounds__(256) void transpose_cvt_kernel(
    const float* __restrict__ W, __hip_bfloat16* __restrict__ Wt, int K, int N) {
    __shared__ float t[32][33];
    int bn = blockIdx.x * 32, bk = blockIdx.y * 32;
    int tx = threadIdx.x & 31, ty = threadIdx.x >> 5;
    for (int r = ty; r < 32; r += 8)
        t[r][tx] = (bn + tx < N) ? W[(size_t)(bk + r) * N + bn + tx] : 0.0f;
    __syncthreads();
    for (int r = ty; r < 32; r += 8) {
        int n = bn + r;
        if (n < N) Wt[(size_t)n * K + bk + tx] = __float2bfloat16(t[tx][r]);
    }
}

// ---------------- ALL weight transposes in one launch (big-ws path) ----------------
__global__ __launch_bounds__(256) void transpose_all_kernel(
    const float* __restrict__ wq, const float* __restrict__ wk,
    const float* __restrict__ wv, const float* __restrict__ wo,
    const float* __restrict__ fc_w, const float* __restrict__ proj_w,
    const float* __restrict__ out_w, __hip_bfloat16* __restrict__ Wt_all) {
    int bid = blockIdx.x;
    const float* W;
    __hip_bfloat16* Wt;
    int K, N, tn, tk;
    if (bid < 6 * 6912) {
        int l = bid / 6912, r = bid % 6912;
        __hip_bfloat16* base = Wt_all + (size_t)l * PL;
        if (r < 1728) {
            int which = r / 576, idx = r % 576;
            W = (which == 0 ? wq : (which == 1 ? wk : wv)) + (size_t)l * DD * DD;
            Wt = base + (size_t)which * DD * DD;
            K = DD; N = DD; tn = idx % 24; tk = idx / 24;
        } else if (r < 2304) {
            int idx = r - 1728;
            W = wo + (size_t)l * DD * DD;
            Wt = base + OFF_WO;
            K = DD; N = DD; tn = idx % 24; tk = idx / 24;
        } else if (r < 4608) {
            int idx = r - 2304;
            W = fc_w + (size_t)l * DD * FF;
            Wt = base + OFF_FC;
            K = DD; N = FF; tn = idx % 96; tk = idx / 96;
        } else {
            int idx = r - 4608;
            W = proj_w + (size_t)l * FF * DD;
            Wt = base + OFF_PROJ;
            K = FF; N = DD; tn = idx % 24; tk = idx / 24;
        }
    } else {
        int idx = bid - 6 * 6912;
        W = out_w;
        Wt = Wt_all + (size_t)6 * PL;
        K = DD; N = VV; tn = idx % 1571; tk = idx / 1571;
    }
    __shared__ float t[32][33];
    int bn = tn * 32, bk = tk * 32;
    int tx = threadIdx.x & 31, ty = threadIdx.x >> 5;
    for (int r = ty; r < 32; r += 8)
        t[r][tx] = (bn + tx < N) ? W[(size_t)(bk + r) * N + bn + tx] : 0.0f;
    __syncthreads();
    for (int r = ty; r < 32; r += 8) {
        int n = bn + r;
        if (n < N) Wt[(size_t)n * K + bk + tx] = __float2bfloat16(t[tx][r]);
    }
}

// LDS rows are 64B (32 bf16); 16B slots XOR-swizzled by ((row>>1)&3).
#define LDSOFF(row, ks) (((row) * 64) + ((((ks) ^ (((row) >> 1) & 3))) << 4))
// swizzled byte offset within a [rows][128B] LDS tile (flash attn)
#define SWZ128(row, byteoff) \
    ((row) * 128 + (((((byteoff) >> 4) ^ ((row) & 7)) & 7) << 4) + ((byteoff) & 15))

// XCD-grouped, M-fastest tile remap. nblk must be launched 1-D.
__device__ __forceinline__ void tile_remap(int mtiles, int BM, int BN, int& bm, int& bn) {
    const int nblk = gridDim.x;
    int hw = blockIdx.x, j = hw;
    if ((nblk & 7) == 0) j = (hw & 7) * (nblk >> 3) + (hw >> 3);
    bm = (j % mtiles) * BM;
    bn = (j / mtiles) * BN;
}

// ============ 256x256 double-buffered GEMM (logits-class) ============
__global__ __launch_bounds__(512) void gemm256_kernel(
    const __hip_bfloat16* __restrict__ A, const __hip_bfloat16* __restrict__ Wt,
    const float* __restrict__ bias, float* __restrict__ Cf,
    __hip_bfloat16* __restrict__ Cb, int M, int N, int K, int do_gelu, int mtiles) {
    __shared__ __align__(16) char lds[65536];
    const int tid = threadIdx.x;
    const int lane = tid & 63;
    const int w = tid >> 6;                // 0..7
    const int wr = w >> 2, wc = w & 3;     // wave grid 2(M) x 4(N)
    const int r16 = lane & 15, kg = lane >> 4;
    int bm, bn;
    tile_remap(mtiles, 256, 256, bm, bn);

    auto STAGE = [&](int T) {
        char* lb = lds + (T & 1) * 32768;
        int k0 = T * 32;
#pragma unroll
        for (int u = 0; u < 2; ++u) {
            int cb = w * 128 + u * 64;     // wave-uniform chunk base
            int c = cb + lane;
            int row = c >> 2;              // 4x16B chunks per 64B row
            int sc = ((c & 3) ^ ((row >> 1) & 3)) * 8;   // inverse-swizzled k-slot
            gload16(A + (size_t)(bm + row) * K + k0 + sc, lb + cb * 16);
            gload16(Wt + (size_t)(bn + row) * K + k0 + sc, lb + 16384 + cb * 16);
        }
    };

    f32x4 acc[8][4];
    const f32x4 zf = {0.0f, 0.0f, 0.0f, 0.0f};
#pragma unroll
    for (int i = 0; i < 8; ++i)
#pragma unroll
        for (int j = 0; j < 4; ++j) acc[i][j] = zf;

    unsigned aoff[8], boff[4];
#pragma unroll
    for (int i = 0; i < 8; ++i) aoff[i] = LDSOFF(wr * 128 + i * 16 + r16, kg);
#pragma unroll
    for (int j = 0; j < 4; ++j) boff[j] = 16384 + LDSOFF(wc * 64 + j * 16 + r16, kg);
    const unsigned lbase = lds_off(lds);

    STAGE(0); STAGE(1);                    // 8 loads/wave in flight
    const int NT = K >> 5;
    for (int t = 0; t < NT; ++t) {
        if (t < NT - 1) asm volatile("s_waitcnt vmcnt(4)" ::: "memory");
        else            asm volatile("s_waitcnt vmcnt(0)" ::: "memory");
        __builtin_amdgcn_s_barrier();      // tile t globally complete
        __builtin_amdgcn_sched_barrier(0);
        unsigned ab = lbase + (unsigned)(t & 1) * 32768u;
        short8v af[8], bf[4];
#pragma unroll
        for (int i = 0; i < 8; ++i) af[i] = ds_read128(ab + aoff[i]);
#pragma unroll
        for (int j = 0; j < 4; ++j) bf[j] = ds_read128(ab + boff[j]);
        asm volatile("s_waitcnt lgkmcnt(0)" ::: "memory");
        __builtin_amdgcn_sched_barrier(0); // rule 18: pin everything below the wait
        __builtin_amdgcn_s_barrier();      // all waves done READING buf[t&1]
        if (t + 2 < NT) STAGE(t + 2);      // overwrite buf[t&1] for tile t+2
        __builtin_amdgcn_s_setprio(1);
#pragma unroll
        for (int i = 0; i < 8; ++i)
#pragma unroll
            for (int j = 0; j < 4; ++j)
                acc[i][j] = __builtin_amdgcn_mfma_f32_16x16x32_bf16(
                    af[i], bf[j], acc[i][j], 0, 0, 0);
        __builtin_amdgcn_s_setprio(0);
    }

    const int rg = lane >> 4;
#pragma unroll
    for (int i = 0; i < 8; ++i)
#pragma unroll
        for (int j = 0; j < 4; ++j) {
            int col = bn + wc * 64 + j * 16 + r16;
            if (col < N) {
#pragma unroll
                for (int r = 0; r < 4; ++r) {
                    int row = bm + wr * 128 + i * 16 + rg * 4 + r;
                    float v = acc[i][j][r];
                    if (bias) v += bias[col];
                    if (do_gelu) v = gelu_f(v);
                    if (Cf) Cf[(size_t)row * N + col] = v;
                    else Cb[(size_t)row * N + col] = __float2bfloat16(v);
                }
            }
        }
}

// ============ 128x128 deep-pipelined GEMM (4-buffer, 2 blocks/CU) ============
__global__ __launch_bounds__(256) void gemm128_kernel(
    const __hip_bfloat16* __restrict__ A, const __hip_bfloat16* __restrict__ Wt,
    const float* __restrict__ bias, float* __restrict__ Cf,
    __hip_bfloat16* __restrict__ Cb, int M, int N, int K, int do_gelu, int mtiles) {
    __shared__ __align__(16) char lds[65536];
    const int tid = threadIdx.x;
    const int lane = tid & 63;
    const int w = tid >> 6;                // 0..3
    const int wr = w >> 1, wc = w & 1;     // wave grid 2x2
    const int r16 = lane & 15, kg = lane >> 4;
    int bm, bn;
    tile_remap(mtiles, 128, 128, bm, bn);

    auto STAGE = [&](int T) {
        char* lb = lds + (T & 3) * 16384;
        int k0 = T * 32;
#pragma unroll
        for (int u = 0; u < 2; ++u) {
            int cb = w * 128 + u * 64;     // wave-uniform chunk base (512 chunks/tile)
            int c = cb + lane;
            int row = c >> 2;
            int sc = ((c & 3) ^ ((row >> 1) & 3)) * 8;
            gload16(A + (size_t)(bm + row) * K + k0 + sc, lb + cb * 16);
            gload16(Wt + (size_t)(bn + row) * K + k0 + sc, lb + 8192 + cb * 16);
        }
    };

    f32x4 acc[4][4];
    const f32x4 zf = {0.0f, 0.0f, 0.0f, 0.0f};
#pragma unroll
    for (int i = 0; i < 4; ++i)
#pragma unroll
        for (int j = 0; j < 4; ++j) acc[i][j] = zf;

    unsigned aoff[4], boff[4];
#pragma unroll
    for (int i = 0; i < 4; ++i) aoff[i] = LDSOFF(wr * 64 + i * 16 + r16, kg);
#pragma unroll
    for (int j = 0; j < 4; ++j) boff[j] = 8192 + LDSOFF(wc * 64 + j * 16 + r16, kg);
    const unsigned lbase = lds_off(lds);

    STAGE(0); STAGE(1); STAGE(2);
    const int NT = K >> 5;
    for (int t = 0; t < NT; ++t) {
        if (t < NT - 2)       asm volatile("s_waitcnt vmcnt(8)" ::: "memory");
        else if (t == NT - 2) asm volatile("s_waitcnt vmcnt(4)" ::: "memory");
        else                  asm volatile("s_waitcnt vmcnt(0)" ::: "memory");
        __builtin_amdgcn_s_barrier();
        __builtin_amdgcn_sched_barrier(0);
        if (t + 3 < NT) STAGE(t + 3);
        unsigned ab = lbase + (unsigned)(t & 3) * 16384u;
        short8v af[4], bf[4];
#pragma unroll
        for (int i = 0; i < 4; ++i) af[i] = ds_read128(ab + aoff[i]);
#pragma unroll
        for (int j = 0; j < 4; ++j) bf[j] = ds_read128(ab + boff[j]);
        asm volatile("s_waitcnt lgkmcnt(0)" ::: "memory");
        __builtin_amdgcn_sched_barrier(0);
        __builtin_amdgcn_s_setprio(1);
#pragma unroll
        for (int i = 0; i < 4; ++i)
#pragma unroll
            for (int j = 0; j < 4; ++j)
                acc[i][j] = __builtin_amdgcn_mfma_f32_16x16x32_bf16(
                    af[i], bf[j], acc[i][j], 0, 0, 0);
        __builtin_amdgcn_s_setprio(0);
    }

    const int rg = lane >> 4;
#pragma unroll
    for (int i = 0; i < 4; ++i)
#pragma unroll
        for (int j = 0; j < 4; ++j) {
            int col = bn + wc * 64 + j * 16 + r16;
#pragma unroll
            for (int r = 0; r < 4; ++r) {
                int row = bm + wr * 64 + i * 16 + rg * 4 + r;
                float v = acc[i][j][r];
                if (bias) v += bias[col];
                if (do_gelu) v = gelu_f(v);
                if (Cf) Cf[(size_t)row * N + col] = v;
                else Cb[(size_t)row * N + col] = __float2bfloat16(v);
            }
        }
}

// ============ 64x64 deep-pipelined GEMM (wo/proj-class, full-grid fill) ============
__global__ __launch_bounds__(256) void gemm64_kernel(
    const __hip_bfloat16* __restrict__ A, const __hip_bfloat16* __restrict__ Wt,
    const float* __restrict__ bias, const float* __restrict__ residual,
    float* __restrict__ Cf, __hip_bfloat16* __restrict__ Cb,
    int M, int N, int K, int do_gelu, int mtiles) {
    __shared__ __align__(16) char lds[32768];
    const int tid = threadIdx.x;
    const int lane = tid & 63;
    const int w = tid >> 6;                // 0..3
    const int wr = w >> 1, wc = w & 1;
    const int r16 = lane & 15, kg = lane >> 4;
    int bm, bn;
    tile_remap(mtiles, 64, 64, bm, bn);

    auto STAGE = [&](int T) {
        char* lb = lds + (T & 3) * 8192;
        int k0 = T * 32;
        int cb = w * 64;                   // 256 chunks/tile, 1 per thread
        int c = cb + lane;
        int row = c >> 2;
        int sc = ((c & 3) ^ ((row >> 1) & 3)) * 8;
        gload16(A + (size_t)(bm + row) * K + k0 + sc, lb + cb * 16);
        gload16(Wt + (size_t)(bn + row) * K + k0 + sc, lb + 4096 + cb * 16);
    };

    f32x4 acc[2][2];
    const f32x4 zf = {0.0f, 0.0f, 0.0f, 0.0f};
#pragma unroll
    for (int i = 0; i < 2; ++i)
#pragma unroll
        for (int j = 0; j < 2; ++j) acc[i][j] = zf;

    unsigned aoff[2], boff[2];
#pragma unroll
    for (int i = 0; i < 2; ++i) aoff[i] = LDSOFF(wr * 32 + i * 16 + r16, kg);
#pragma unroll
    for (int j = 0; j < 2; ++j) boff[j] = 4096 + LDSOFF(wc * 32 + j * 16 + r16, kg);
    const unsigned lbase = lds_off(lds);

    STAGE(0); STAGE(1); STAGE(2);          // 6 loads/wave in flight
    const int NT = K >> 5;
    for (int t = 0; t < NT; ++t) {
        if (t < NT - 2)       asm volatile("s_waitcnt vmcnt(4)" ::: "memory");
        else if (t == NT - 2) asm volatile("s_waitcnt vmcnt(2)" ::: "memory");
        else                  asm volatile("s_waitcnt vmcnt(0)" ::: "memory");
        __builtin_amdgcn_s_barrier();
        __builtin_amdgcn_sched_barrier(0);
        if (t + 3 < NT) STAGE(t + 3);
        unsigned ab = lbase + (unsigned)(t & 3) * 8192u;
        short8v af[2], bf[2];
#pragma unroll
        for (int i = 0; i < 2; ++i) af[i] = ds_read128(ab + aoff[i]);
#pragma unroll
        for (int j = 0; j < 2; ++j) bf[j] = ds_read128(ab + boff[j]);
        asm volatile("s_waitcnt lgkmcnt(0)" ::: "memory");
        __builtin_amdgcn_sched_barrier(0);
        __builtin_amdgcn_s_setprio(1);
#pragma unroll
        for (int i = 0; i < 2; ++i)
#pragma unroll
            for (int j = 0; j < 2; ++j)
                acc[i][j] = __builtin_amdgcn_mfma_f32_16x16x32_bf16(
                    af[i], bf[j], acc[i][j], 0, 0, 0);
        __builtin_amdgcn_s_setprio(0);
    }

    const int rg = lane >> 4;
#pragma unroll
    for (int i = 0; i < 2; ++i)
#pragma unroll
        for (int j = 0; j < 2; ++j) {
            int col = bn + wc * 32 + j * 16 + r16;
#pragma unroll
            for (int r = 0; r < 4; ++r) {
                int row = bm + wr * 32 + i * 16 + rg * 4 + r;
                float v = acc[i][j][r];
                if (bias) v += bias[col];
                if (do_gelu) v = gelu_f(v);
                size_t o = (size_t)row * N + col;
                if (residual) v += residual[o];
                if (Cf) Cf[o] = v;
                else Cb[o] = __float2bfloat16(v);
            }
        }
}

// ============ QKV deep-pipelined 128x128 GEMM with head-split epilogue ============
__global__ __launch_bounds__(256) void qkv_gemm_kernel(
    const __hip_bfloat16* __restrict__ A, const __hip_bfloat16* __restrict__ Wt,
    __hip_bfloat16* __restrict__ qh, __hip_bfloat16* __restrict__ kh,
    __hip_bfloat16* __restrict__ vt) {
    constexpr int K = DD;
    __shared__ __align__(16) char lds[65536];
    const int tid = threadIdx.x;
    const int lane = tid & 63;
    const int w = tid >> 6;
    const int wr = w >> 1, wc = w & 1;
    const int r16 = lane & 15, kg = lane >> 4;
    int bm, bn;
    tile_remap(16, 128, 128, bm, bn);

    auto STAGE = [&](int T) {
        char* lb = lds + (T & 3) * 16384;
        int k0 = T * 32;
#pragma unroll
        for (int u = 0; u < 2; ++u) {
            int cb = w * 128 + u * 64;
            int c = cb + lane;
            int row = c >> 2;
            int sc = ((c & 3) ^ ((row >> 1) & 3)) * 8;
            gload16(A + (size_t)(bm + row) * K + k0 + sc, lb + cb * 16);
            gload16(Wt + (size_t)(bn + row) * K + k0 + sc, lb + 8192 + cb * 16);
        }
    };

    f32x4 acc[4][4];
    const f32x4 zf = {0.0f, 0.0f, 0.0f, 0.0f};
#pragma unroll
    for (int i = 0; i < 4; ++i)
#pragma unroll
        for (int j = 0; j < 4; ++j) acc[i][j] = zf;

    unsigned aoff[4], boff[4];
#pragma unroll
    for (int i = 0; i < 4; ++i) aoff[i] = LDSOFF(wr * 64 + i * 16 + r16, kg);
#pragma unroll
    for (int j = 0; j < 4; ++j) boff[j] = 8192 + LDSOFF(wc * 64 + j * 16 + r16, kg);
    const unsigned lbase = lds_off(lds);

    STAGE(0); STAGE(1); STAGE(2);
    const int NT = K >> 5;                 // 24
    for (int t = 0; t < NT; ++t) {
        if (t < NT - 2)       asm volatile("s_waitcnt vmcnt(8)" ::: "memory");
        else if (t == NT - 2) asm volatile("s_waitcnt vmcnt(4)" ::: "memory");
        else                  asm volatile("s_waitcnt vmcnt(0)" ::: "memory");
        __builtin_amdgcn_s_barrier();
        __builtin_amdgcn_sched_barrier(0);
        if (t + 3 < NT) STAGE(t + 3);
        unsigned ab = lbase + (unsigned)(t & 3) * 16384u;
        short8v af[4], bf[4];
#pragma unroll
        for (int i = 0; i < 4; ++i) af[i] = ds_read128(ab + aoff[i]);
#pragma unroll
        for (int j = 0; j < 4; ++j) bf[j] = ds_read128(ab + boff[j]);
        asm volatile("s_waitcnt lgkmcnt(0)" ::: "memory");
        __builtin_amdgcn_sched_barrier(0);
        __builtin_amdgcn_s_setprio(1);
#pragma unroll
        for (int i = 0; i < 4; ++i)
#pragma unroll
            for (int j = 0; j < 4; ++j)
                acc[i][j] = __builtin_amdgcn_mfma_f32_16x16x32_bf16(
                    af[i], bf[j], acc[i][j], 0, 0, 0);
        __builtin_amdgcn_s_setprio(0);
    }

#pragma unroll
    for (int i = 0; i < 4; ++i) {
#pragma unroll
        for (int j = 0; j < 4; ++j) {
            int col = bn + wc * 64 + j * 16 + r16;
#pragma unroll
            for (int r = 0; r < 4; ++r) {
                int row = bm + wr * 64 + i * 16 + kg * 4 + r;   // b*S + s
                int b = row >> 10, s = row & (SS - 1);
                float v = acc[i][j][r];
                if (col < DD) {
                    int h = col >> 6, d = col & 63;
                    qh[((size_t)(b * HH + h) * SS + s) * DKK + d] =
                        __float2bfloat16(v * 0.125f);       // fold 1/sqrt(64)
                } else if (col < 2 * DD) {
                    int c = col - DD, h = c >> 6, d = c & 63;
                    kh[((size_t)(b * HH + h) * SS + s) * DKK + d] = __float2bfloat16(v);
                } else {
                    int c = col - 2 * DD, h = c >> 6, d = c & 63;
                    vt[((size_t)(b * HH + h) * DKK + d) * SS + s] = __float2bfloat16(v);
                }
            }
        }
    }
}

// ---------------- flash attention (T14 + dbuf K/V + T13 defer-max, THR=8) ----------
__global__ __launch_bounds__(256) void flash_attn_kernel(
    const __hip_bfloat16* __restrict__ qh, const __hip_bfloat16* __restrict__ kh,
    const __hip_bfloat16* __restrict__ vt, __hip_bfloat16* __restrict__ ctx) {
    __shared__ __align__(16) char Ks[2][KVBLK * 128];
    __shared__ __align__(16) char Vs[2][DKK * 128];
    __shared__ __align__(16) char Ps[4][16 * 128];

    const int bh = blockIdx.x;
    const int qt = (gridDim.y - 1) - blockIdx.y;
    const int q0 = qt * QBLK;
    const int b = bh / HH;
    const int h = bh - b * HH;
    const int tid = threadIdx.x;
    const int lane = tid & 63;
    const int w = tid >> 6;
    const int r16 = lane & 15;
    const int kg = lane >> 4;
    char* Pw = Ps[w];

    const size_t qbase = ((size_t)bh * SS + q0 + w * 16 + r16) * DKK;
    short8v qf0 = *(const short8v*)(qh + qbase + kg * 8);
    short8v qf1 = *(const short8v*)(qh + qbase + 32 + kg * 8);

    const __hip_bfloat16* kbase = kh + (size_t)bh * SS * DKK;
    const __hip_bfloat16* vbase = vt + (size_t)bh * DKK * SS;
    // this thread's staging coordinates (2 chunks: c and c+256)
    const int row0 = tid >> 3, slot0 = tid & 7;
    const int row1 = (tid + 256) >> 3, slot1 = tid & 7;   // (tid+256)&7 == tid&7

    int4v kreg0, kreg1, vreg0, vreg1;
    {   // prologue: load tile 0 into regs
        kreg0 = *(const int4v*)(kbase + (size_t)row0 * DKK + slot0 * 8);
        kreg1 = *(const int4v*)(kbase + (size_t)row1 * DKK + slot1 * 8);
        vreg0 = *(const int4v*)(vbase + (size_t)row0 * SS + slot0 * 8);
        vreg1 = *(const int4v*)(vbase + (size_t)row1 * SS + slot1 * 8);
    }

    f32x4 acc_o[4];
    const f32x4 zf = {0.0f, 0.0f, 0.0f, 0.0f};
    float m[4], l[4];
#pragma unroll
    for (int j = 0; j < 4; ++j) acc_o[j] = zf;
#pragma unroll
    for (int r = 0; r < 4; ++r) { m[r] = -1e30f; l[r] = 0.0f; }

    const int nt = qt + 1;
    for (int t = 0; t < nt; ++t) {
        // write tile t into buf[t&1]; any lagging wave computing t-1 reads buf[(t-1)&1]
        char* Kb = Ks[t & 1];
        char* Vb = Vs[t & 1];
        *(int4v*)(Kb + SWZ128(row0, slot0 * 16)) = kreg0;
        *(int4v*)(Kb + SWZ128(row1, slot1 * 16)) = kreg1;
        *(int4v*)(Vb + SWZ128(row0, slot0 * 16)) = vreg0;
        *(int4v*)(Vb + SWZ128(row1, slot1 * 16)) = vreg1;
        __syncthreads();   // single barrier: tile t visible to all waves

        if (t + 1 < nt) {  // T14: issue next-tile loads; latency hides under compute
            const __hip_bfloat16* kp = kbase + (size_t)(t + 1) * KVBLK * DKK;
            const __hip_bfloat16* vp = vbase + (t + 1) * KVBLK;
            kreg0 = *(const int4v*)(kp + (size_t)row0 * DKK + slot0 * 8);
            kreg1 = *(const int4v*)(kp + (size_t)row1 * DKK + slot1 * 8);
            vreg0 = *(const int4v*)(vp + (size_t)row0 * SS + slot0 * 8);
            vreg1 = *(const int4v*)(vp + (size_t)row1 * SS + slot1 * 8);
        }

        f32x4 s[4];
#pragma unroll
        for (int j = 0; j < 4; ++j) s[j] = zf;
        __builtin_amdgcn_s_setprio(1);
#pragma unroll
        for (int j = 0; j < 4; ++j) {
            short8v k0f = *(const short8v*)(Kb + SWZ128(j * 16 + r16, kg * 16));
            short8v k1f = *(const short8v*)(Kb + SWZ128(j * 16 + r16, 64 + kg * 16));
            s[j] = __builtin_amdgcn_mfma_f32_16x16x32_bf16(qf0, k0f, s[j], 0, 0, 0);
            s[j] = __builtin_amdgcn_mfma_f32_16x16x32_bf16(qf1, k1f, s[j], 0, 0, 0);
        }
        __builtin_amdgcn_s_setprio(0);

        if (t == qt) {
#pragma unroll
            for (int j = 0; j < 4; ++j)
#pragma unroll
                for (int r = 0; r < 4; ++r)
                    if (j * 16 + r16 > w * 16 + kg * 4 + r) s[j][r] = -1e30f;
        }

        // T13 defer-max: only rescale when some row's tile-max exceeds m+8.
        // P then bounded by e^8 (bf16-safe); softmax ratio exact (same m in num+den).
        float pmax[4];
        bool grew = false;
#pragma unroll
        for (int r = 0; r < 4; ++r) {
            float v = fmaxf(fmaxf(s[0][r], s[1][r]), fmaxf(s[2][r], s[3][r]));
#pragma unroll
            for (int d2 = 1; d2 < 16; d2 <<= 1)
                v = fmaxf(v, __shfl_xor(v, d2));
            pmax[r] = v;
            grew = grew || (v > m[r] + 8.0f);
        }
        if (__any(grew)) {   // wave-uniform (v uniform per 16-lane group)
#pragma unroll
            for (int r = 0; r < 4; ++r) {
                float mnew = fmaxf(m[r], pmax[r]);
                float alpha = __expf(m[r] - mnew);
                m[r] = mnew;
                l[r] *= alpha;
#pragma unroll
                for (int j = 0; j < 4; ++j) acc_o[j][r] *= alpha;
            }
        }

        float rsum[4] = {0.0f, 0.0f, 0.0f, 0.0f};
#pragma unroll
        for (int j = 0; j < 4; ++j)
#pragma unroll
            for (int r = 0; r < 4; ++r) {
                float p = __expf(s[j][r] - m[r]);
                rsum[r] += p;
                *(__hip_bfloat16*)(Pw + SWZ128(kg * 4 + r, (j * 16 + r16) * 2)) =
                    __float2bfloat16(p);
            }
#pragma unroll
        for (int r = 0; r < 4; ++r) {
#pragma unroll
            for (int d2 = 1; d2 < 16; d2 <<= 1)
                rsum[r] += __shfl_xor(rsum[r], d2);
            l[r] += rsum[r];
        }

        short8v pa0 = *(const short8v*)(Pw + SWZ128(r16, kg * 16));
        short8v pa1 = *(const short8v*)(Pw + SWZ128(r16, 64 + kg * 16));
        __builtin_amdgcn_s_setprio(1);
#pragma unroll
        for (int j = 0; j < 4; ++j) {
            short8v v0f = *(const short8v*)(Vb + SWZ128(j * 16 + r16, kg * 16));
            short8v v1f = *(const short8v*)(Vb + SWZ128(j * 16 + r16, 64 + kg * 16));
            acc_o[j] = __builtin_amdgcn_mfma_f32_16x16x32_bf16(pa0, v0f, acc_o[j], 0, 0, 0);
            acc_o[j] = __builtin_amdgcn_mfma_f32_16x16x32_bf16(pa1, v1f, acc_o[j], 0, 0, 0);
        }
        __builtin_amdgcn_s_setprio(0);
    }

#pragma unroll
    for (int r = 0; r < 4; ++r) {
        float inv = 1.0f / l[r];
        int row = q0 + w * 16 + kg * 4 + r;
        __hip_bfloat16* cp = ctx + ((size_t)(b * SS) + row) * DD + h * DKK;
#pragma unroll
        for (int j = 0; j < 4; ++j)
            cp[j * 16 + r16] = __float2bfloat16(acc_o[j][r] * inv);
    }
}

// ---------------- fp32 fallback GEMM / attention ----------------
__global__ __launch_bounds__(256) void gemm_kernel(
    const float* __restrict__ A, const float* __restrict__ W,
    const float* __restrict__ bias, const float* __restrict__ residual,
    float* __restrict__ C, int M, int N, int K, int do_gelu) {
    __shared__ float As[16][64];
    __shared__ float Ws[16][68];
    int tid = threadIdx.x;
    int bn = blockIdx.x * 64, bm = blockIdx.y * 64;
    int tx = tid & 15, ty = tid >> 4;
    int ar = tid >> 2, ak = (tid & 3) << 2;
    int wr = tid >> 4, wc = (tid & 15) << 2;
    bool n_vec = ((N & 3) == 0);
    float acc[4][4] = {};
    for (int k0 = 0; k0 < K; k0 += 16) {
        float4 av = *(const float4*)&A[(size_t)(bm + ar) * K + (k0 + ak)];
        As[ak + 0][ar] = av.x; As[ak + 1][ar] = av.y;
        As[ak + 2][ar] = av.z; As[ak + 3][ar] = av.w;
        int gn = bn + wc;
        const float* wp = &W[(size_t)(k0 + wr) * N + gn];
        float w0, w1, w2, w3;
        if (n_vec && gn + 3 < N) {
            float4 wv4 = *(const float4*)wp;
            w0 = wv4.x; w1 = wv4.y; w2 = wv4.z; w3 = wv4.w;
        } else {
            w0 = (gn + 0 < N) ? wp[0] : 0.0f;
            w1 = (gn + 1 < N) ? wp[1] : 0.0f;
            w2 = (gn + 2 < N) ? wp[2] : 0.0f;
            w3 = (gn + 3 < N) ? wp[3] : 0.0f;
        }
        Ws[wr][wc + 0] = w0; Ws[wr][wc + 1] = w1;
        Ws[wr][wc + 2] = w2; Ws[wr][wc + 3] = w3;
        __syncthreads();
#pragma unroll
        for (int kk = 0; kk < 16; ++kk) {
            float a[4], w[4];
#pragma unroll
            for (int i = 0; i < 4; ++i) a[i] = As[kk][ty * 4 + i];
#pragma unroll
            for (int j = 0; j < 4; ++j) w[j] = Ws[kk][tx * 4 + j];
#pragma unroll
            for (int i = 0; i < 4; ++i)
#pragma unroll
                for (int j = 0; j < 4; ++j)
                    acc[i][j] = fmaf(a[i], w[j], acc[i][j]);
        }
        __syncthreads();
    }
#pragma unroll
    for (int i = 0; i < 4; ++i) {
        int row = bm + ty * 4 + i;
#pragma unroll
        for (int j = 0; j < 4; ++j) {
            int col = bn + tx * 4 + j;
            if (col < N) {
                float val = acc[i][j];
                if (bias) val += bias[col];
                if (do_gelu) val = gelu_f(val);
                if (residual) val += residual[(size_t)row * N + col];
                C[(size_t)row * N + col] = val;
            }
        }
    }
}

__global__ __launch_bounds__(256) void attn_kernel(
    const float* __restrict__ q, const float* __restrict__ k,
    const float* __restrict__ v, float* __restrict__ ctx) {
    int bid = blockIdx.x;
    int qi = bid & (SS - 1);
    int bh = bid >> 10;
    int h = bh % HH;
    int b = bh / HH;
    int tid = threadIdx.x;
    __shared__ float qs[DKK];
    __shared__ float p[SS];
    __shared__ float red[256];
    __shared__ float ctx_red[4][DKK];
    const float* qrow = q + ((size_t)(b * SS + qi)) * DD + h * DKK;
    if (tid < DKK) qs[tid] = qrow[tid];
    __syncthreads();
    int nk = qi + 1;
    const float scale = 0.125f;
    for (int ki = tid; ki < nk; ki += 256) {
        const float* krow = k + ((size_t)(b * SS + ki)) * DD + h * DKK;
        float dot = 0.0f;
#pragma unroll
        for (int d = 0; d < DKK; d += 4) {
            float4 kv = *(const float4*)&krow[d];
            dot += qs[d] * kv.x + qs[d + 1] * kv.y + qs[d + 2] * kv.z + qs[d + 3] * kv.w;
        }
        p[ki] = dot * scale;
    }
    __syncthreads();
    float lmax = -1e30f;
    for (int ki = tid; ki < nk; ki += 256) lmax = fmaxf(lmax, p[ki]);
    red[tid] = lmax;
    __syncthreads();
    for (int s2 = 128; s2 > 0; s2 >>= 1) {
        if (tid < s2) red[tid] = fmaxf(red[tid], red[tid + s2]);
        __syncthreads();
    }
    float mm = red[0];
    __syncthreads();
    float lsum = 0.0f;
    for (int ki = tid; ki < nk; ki += 256) {
        float e = __expf(p[ki] - mm);
        p[ki] = e;
        lsum += e;
    }
    red[tid] = lsum;
    __syncthreads();
    for (int s2 = 128; s2 > 0; s2 >>= 1) {
        if (tid < s2) red[tid] += red[tid + s2];
        __syncthreads();
    }
    float inv = 1.0f / red[0];
    int d = tid & 63;
    int chunk = tid >> 6;
    float accd = 0.0f;
    for (int ki = chunk; ki < nk; ki += 4)
        accd += p[ki] * v[((size_t)(b * SS + ki)) * DD + h * DKK + d];
    ctx_red[chunk][d] = accd;
    __syncthreads();
    if (tid < DKK) {
        float sum = (ctx_red[0][tid] + ctx_red[1][tid]) + (ctx_red[2][tid] + ctx_red[3][tid]);
        ctx[((size_t)(b * SS + qi)) * DD + h * DKK + tid] = sum * inv;
    }
}

// ---------------- host-side orchestration ----------------
extern "C" void kernel_launch(void* const* d_in, const int* in_sizes, int n_in,
                              void* d_out, int out_size, void* d_ws, size_t ws_size,
                              hipStream_t stream) {
    const int*   ids    = (const int*)  d_in[0];
    const float* tok    = (const float*)d_in[1];
    const float* pos    = (const float*)d_in[2];
    const float* wq     = (const float*)d_in[3];
    const float* wk     = (const float*)d_in[4];
    const float* wv     = (const float*)d_in[5];
    const float* wo     = (const float*)d_in[6];
    const float* bo     = (const float*)d_in[7];
    const float* fc_w   = (const float*)d_in[8];
    const float* fc_b   = (const float*)d_in[9];
    const float* proj_w = (const float*)d_in[10];
    const float* proj_b = (const float*)d_in[11];
    const float* ln1_g  = (const float*)d_in[12];
    const float* ln1_b  = (const float*)d_in[13];
    const float* ln2_g  = (const float*)d_in[14];
    const float* ln2_b  = (const float*)d_in[15];
    const float* lnf_g  = (const float*)d_in[16];
    const float* lnf_b  = (const float*)d_in[17];
    const float* out_w  = (const float*)d_in[18];
    float* out = (float*)d_out;

    dim3 blk(256);

    const size_t SZ_X    = (size_t)NROWS * DD * 4;
    const size_t SZ_XN   = (size_t)NROWS * DD * 2;
    const size_t SZ_HD   = (size_t)BB * HH * SS * DKK * 2;
    const size_t SZ_CTX  = (size_t)NROWS * DD * 2;
    const size_t SZ_H    = (size_t)NROWS * FF * 2;
    const size_t SZ_WT1  = (size_t)VPAD * DD * 2;                      // shared (mid)
    const size_t SZ_WTA  = ((size_t)6 * PL + (size_t)VPAD * DD) * 2;   // all (big)
    const size_t ACT     = SZ_X + SZ_XN + 3 * SZ_HD + SZ_CTX + SZ_H;
    const size_t NEED_MID = ACT + SZ_WT1;
    const size_t NEED_BIG = ACT + SZ_WTA;

    if (ws_size >= NEED_MID) {
        const bool big = (ws_size >= NEED_BIG);
        char* p = (char*)d_ws;
        float*          x    = (float*)p;          p += SZ_X;
        __hip_bfloat16* xn   = (__hip_bfloat16*)p; p += SZ_XN;
        __hip_bfloat16* qhb  = (__hip_bfloat16*)p; p += SZ_HD;
        __hip_bfloat16* khb  = (__hip_bfloat16*)p; p += SZ_HD;
        __hip_bfloat16* vtb  = (__hip_bfloat16*)p; p += SZ_HD;
        __hip_bfloat16* ctx  = (__hip_bfloat16*)p; p += SZ_CTX;
        __hip_bfloat16* hbuf = (__hip_bfloat16*)p; p += SZ_H;
        __hip_bfloat16* Wt   = (__hip_bfloat16*)p;

        dim3 tD(DD / 32, DD / 32);
        dim3 tF(FF / 32, DD / 32);
        dim3 tP(DD / 32, FF / 32);
        dim3 tV((VV + 31) / 32, DD / 32);

        const int nQKV = (QKVN / 128) * (NROWS / 128);       // 288 (128^2 deep-pipe)
        const int nWO  = (DD / 64) * (NROWS / 64);           // 384 (64^2 deep-pipe)
        const int nFC  = (FF / 128) * (NROWS / 128);         // 384 (128^2 deep-pipe)
        const int nV   = (VPAD / 256) * (NROWS / 256);       // 1576 (256^2 dbuf)
        dim3 gA(BB * HH, SS / QBLK);                         // 24 x 16

        if (big)
            transpose_all_kernel<<<6 * 6912 + 37704, blk, 0, stream>>>(
                wq, wk, wv, wo, fc_w, proj_w, out_w, Wt);

        embed_kernel<<<NROWS, blk, 0, stream>>>(ids, tok, pos, x);

        for (int l = 0; l < LL; ++l) {
            __hip_bfloat16* qkvWt = big ? Wt + (size_t)l * PL : Wt;
            __hip_bfloat16* woWt  = big ? Wt + (size_t)l * PL + OFF_WO : Wt;
            __hip_bfloat16* fcWt  = big ? Wt + (size_t)l * PL + OFF_FC : Wt;
            __hip_bfloat16* pjWt  = big ? Wt + (size_t)l * PL + OFF_PROJ : Wt;

            ln_bf16_kernel<<<NROWS, blk, 0, stream>>>(x, ln1_g + l * DD, ln1_b + l * DD, xn);
            if (!big) {
                transpose_cvt_kernel<<<tD, blk, 0, stream>>>(wq + (size_t)l * DD * DD, qkvWt, DD, DD);
                transpose_cvt_kernel<<<tD, blk, 0, stream>>>(wk + (size_t)l * DD * DD, qkvWt + (size_t)DD * DD, DD, DD);
                transpose_cvt_kernel<<<tD, blk, 0, stream>>>(wv + (size_t)l * DD * DD, qkvWt + (size_t)2 * DD * DD, DD, DD);
            }
            qkv_gemm_kernel<<<nQKV, blk, 0, stream>>>(xn, qkvWt, qhb, khb, vtb);
            flash_attn_kernel<<<gA, blk, 0, stream>>>(qhb, khb, vtb, ctx);
            if (!big)
                transpose_cvt_kernel<<<tD, blk, 0, stream>>>(wo + (size_t)l * DD * DD, woWt, DD, DD);
            gemm64_kernel<<<nWO, blk, 0, stream>>>(
                ctx, woWt, bo + l * DD, x, x, nullptr, NROWS, DD, DD, 0, NROWS / 64);
            ln_bf16_kernel<<<NROWS, blk, 0, stream>>>(x, ln2_g + l * DD, ln2_b + l * DD, xn);
            if (!big)
                transpose_cvt_kernel<<<tF, blk, 0, stream>>>(fc_w + (size_t)l * DD * FF, fcWt, DD, FF);
            gemm128_kernel<<<nFC, blk, 0, stream>>>(
                xn, fcWt, fc_b + l * FF, nullptr, hbuf, NROWS, FF, DD, 1, NROWS / 128);
            if (!big)
                transpose_cvt_kernel<<<tP, blk, 0, stream>>>(proj_w + (size_t)l * FF * DD, pjWt, FF, DD);
            gemm64_kernel<<<nWO, blk, 0, stream>>>(
                hbuf, pjWt, proj_b + l * DD, x, x, nullptr, NROWS, DD, FF, 0, NROWS / 64);
        }

        __hip_bfloat16* outWt = big ? Wt + (size_t)6 * PL : Wt;
        ln_bf16_kernel<<<NROWS, blk, 0, stream>>>(x, lnf_g, lnf_b, xn);
        if (!big)
            transpose_cvt_kernel<<<tV, blk, 0, stream>>>(out_w, outWt, DD, VV);
        gemm256_kernel<<<nV, 512, 0, stream>>>(
            xn, outWt, nullptr, out, nullptr, NROWS, VV, DD, 0, NROWS / 256);
        return;
    }

    // ---- fallback: proven fp32 path ----
    const size_t XSZ = (size_t)NROWS * DD;
    float* ws = (float*)d_ws;
    float* x  = ws;
    float* xn = x  + XSZ;
    float* qb = xn + XSZ;
    float* kb = qb + XSZ;
    float* vb = kb + XSZ;
    float* cb = vb + XSZ;
    float* hb = cb + XSZ;

    dim3 gD((DD + 63) / 64, NROWS / 64);
    dim3 gF((FF + 63) / 64, NROWS / 64);
    dim3 gV2((VV + 63) / 64, NROWS / 64);

    embed_kernel<<<NROWS, blk, 0, stream>>>(ids, tok, pos, x);
    for (int l = 0; l < LL; ++l) {
        const float* wq_l = wq + (size_t)l * DD * DD;
        const float* wk_l = wk + (size_t)l * DD * DD;
        const float* wv_l = wv + (size_t)l * DD * DD;
        const float* wo_l = wo + (size_t)l * DD * DD;
        const float* fc_w_l = fc_w + (size_t)l * DD * FF;
        const float* pj_w_l = proj_w + (size_t)l * FF * DD;
        ln_kernel<<<NROWS, blk, 0, stream>>>(x, ln1_g + l * DD, ln1_b + l * DD, xn);
        gemm_kernel<<<gD, blk, 0, stream>>>(xn, wq_l, nullptr, nullptr, qb, NROWS, DD, DD, 0);
        gemm_kernel<<<gD, blk, 0, stream>>>(xn, wk_l, nullptr, nullptr, kb, NROWS, DD, DD, 0);
        gemm_kernel<<<gD, blk, 0, stream>>>(xn, wv_l, nullptr, nullptr, vb, NROWS, DD, DD, 0);
        attn_kernel<<<BB * HH * SS, blk, 0, stream>>>(qb, kb, vb, cb);
        gemm_kernel<<<gD, blk, 0, stream>>>(cb, wo_l, bo + l * DD, x, x, NROWS, DD, DD, 0);
        ln_kernel<<<NROWS, blk, 0, stream>>>(x, ln2_g + l * DD, ln2_b + l * DD, xn);
        gemm_kernel<<<gF, blk, 0, stream>>>(xn, fc_w_l, fc_b + l * FF, nullptr, hb, NROWS, FF, DD, 1);
        gemm_kernel<<<gD, blk, 0, stream>>>(hb, pj_w_l, proj_b + l * DD, x, x, NROWS, DD, FF, 0);
    }
    ln_kernel<<<NROWS, blk, 0, stream>>>(x, lnf_g, lnf_b, xn);
    gemm_kernel<<<gV2, blk, 0, stream>>>(xn, out_w, nullptr, nullptr, out, NROWS, VV, DD, 0);
}

// Round 16
// 1372.745 us; speedup vs baseline: 1.0044x; 1.0044x over previous
//
#include <hip/hip_runtime.h>
#include <hip/hip_bf16.h>
#include <math.h>

// GPT-2 small forward: B=2, S=1024, V=50257, D=768, H=12, L=6, F=3072, DK=64
#define BB 2
#define SS 1024
#define DD 768
#define HH 12
#define LL 6
#define FF 3072
#define VV 50257
#define DKK 64
#define NROWS (BB * SS)   // 2048
#define QKVN (3 * DD)     // 2304
#define QBLK 64
#define KVBLK 64
#define VPAD 50432        // 197*256 = logits N padded to 256-tile boundary

// Wt_all element layout per layer: [qkv 2304x768 | wo 768x768 | fc 3072x768 | proj 768x3072]
#define OFF_QKV 0
#define OFF_WO  1769472
#define OFF_FC  2359296
#define OFF_PROJ 4718592
#define PL      7077888   // elements per layer

typedef __attribute__((ext_vector_type(8))) short short8v;  // 8 bf16 = 4 VGPRs
typedef __attribute__((ext_vector_type(4))) float f32x4;
typedef __attribute__((ext_vector_type(4))) int int4v;

__device__ __forceinline__ float gelu_f(float x) {
    return 0.5f * x * (1.0f + erff(x * 0.70710678118654752440f));
}

// async 16B global->LDS DMA (dest = wave-uniform base + lane*16)
__device__ __forceinline__ void gload16(const void* g, void* l) {
    __builtin_amdgcn_global_load_lds(
        (const __attribute__((address_space(1))) void*)g,
        (__attribute__((address_space(3))) void*)l, 16, 0, 0);
}
// LDS byte offset of a __shared__ pointer (AS3 pointers are 32-bit)
__device__ __forceinline__ unsigned lds_off(const void* p) {
    return (unsigned)(size_t)(const __attribute__((address_space(3))) char*)p;
}
// raw ds_read_b128 — opaque to the waitcnt pass (counted-lgkmcnt discipline)
__device__ __forceinline__ short8v ds_read128(unsigned addr) {
    short8v r;
    asm volatile("ds_read_b128 %0, %1" : "=v"(r) : "v"(addr));
    return r;
}

// ---------------- embedding ----------------
__global__ __launch_bounds__(256) void embed_kernel(
    const int* __restrict__ ids, const float* __restrict__ tok,
    const float* __restrict__ pos, float* __restrict__ x) {
    int row = blockIdx.x;
    int s = row & (SS - 1);
    int id = ids[row];
    const float* t = tok + (size_t)id * DD;
    const float* p = pos + (size_t)s * DD;
    float* xr = x + (size_t)row * DD;
    for (int i = threadIdx.x; i < DD; i += 256)
        xr[i] = t[i] + p[i];
}

// ---------------- layernorm (fp32 in, fp32 out) — fallback ----------------
__global__ __launch_bounds__(256) void ln_kernel(
    const float* __restrict__ x, const float* __restrict__ g,
    const float* __restrict__ b, float* __restrict__ out) {
    int row = blockIdx.x;
    int tid = threadIdx.x;
    const float* xr = x + (size_t)row * DD;
    float v0 = xr[tid], v1 = xr[tid + 256], v2 = xr[tid + 512];
    __shared__ float red[256];
    red[tid] = v0 + v1 + v2;
    __syncthreads();
    for (int s2 = 128; s2 > 0; s2 >>= 1) {
        if (tid < s2) red[tid] += red[tid + s2];
        __syncthreads();
    }
    float mu = red[0] * (1.0f / DD);
    __syncthreads();
    float d0 = v0 - mu, d1 = v1 - mu, d2 = v2 - mu;
    red[tid] = d0 * d0 + d1 * d1 + d2 * d2;
    __syncthreads();
    for (int s2 = 128; s2 > 0; s2 >>= 1) {
        if (tid < s2) red[tid] += red[tid + s2];
        __syncthreads();
    }
    float r = rsqrtf(red[0] * (1.0f / DD) + 1e-5f);
    float* o = out + (size_t)row * DD;
    o[tid]       = d0 * r * g[tid]       + b[tid];
    o[tid + 256] = d1 * r * g[tid + 256] + b[tid + 256];
    o[tid + 512] = d2 * r * g[tid + 512] + b[tid + 512];
}

// ---------------- layernorm (fp32 in, bf16 out) ----------------
__global__ __launch_bounds__(256) void ln_bf16_kernel(
    const float* __restrict__ x, const float* __restrict__ g,
    const float* __restrict__ b, __hip_bfloat16* __restrict__ out) {
    int row = blockIdx.x;
    int tid = threadIdx.x;
    const float* xr = x + (size_t)row * DD;
    float v0 = xr[tid], v1 = xr[tid + 256], v2 = xr[tid + 512];
    __shared__ float red[256];
    red[tid] = v0 + v1 + v2;
    __syncthreads();
    for (int s2 = 128; s2 > 0; s2 >>= 1) {
        if (tid < s2) red[tid] += red[tid + s2];
        __syncthreads();
    }
    float mu = red[0] * (1.0f / DD);
    __syncthreads();
    float d0 = v0 - mu, d1 = v1 - mu, d2 = v2 - mu;
    red[tid] = d0 * d0 + d1 * d1 + d2 * d2;
    __syncthreads();
    for (int s2 = 128; s2 > 0; s2 >>= 1) {
        if (tid < s2) red[tid] += red[tid + s2];
        __syncthreads();
    }
    float r = rsqrtf(red[0] * (1.0f / DD) + 1e-5f);
    __hip_bfloat16* o = out + (size_t)row * DD;
    o[tid]       = __float2bfloat16(d0 * r * g[tid]       + b[tid]);
    o[tid + 256] = __float2bfloat16(d1 * r * g[tid + 256] + b[tid + 256]);
    o[tid + 512] = __float2bfloat16(d2 * r * g[tid + 512] + b[tid + 512]);
}

// ---------------- single W [K,N] f32 -> Wt [N,K] bf16 (mid path) ----------------
__global__ __launch_bounds__(256) void transpose_cvt_kernel(
    const float* __restrict__ W, __hip_bfloat16* __restrict__ Wt, int K, int N) {
    __shared__ float t[32][33];
    int bn = blockIdx.x * 32, bk = blockIdx.y * 32;
    int tx = threadIdx.x & 31, ty = threadIdx.x >> 5;
    for (int r = ty; r < 32; r += 8)
        t[r][tx] = (bn + tx < N) ? W[(size_t)(bk + r) * N + bn + tx] : 0.0f;
    __syncthreads();
    for (int r = ty; r < 32; r += 8) {
        int n = bn + r;
        if (n < N) Wt[(size_t)n * K + bk + tx] = __float2bfloat16(t[tx][r]);
    }
}

// ---------------- ALL weight transposes in one launch (big-ws path) ----------------
__global__ __launch_bounds__(256) void transpose_all_kernel(
    const float* __restrict__ wq, const float* __restrict__ wk,
    const float* __restrict__ wv, const float* __restrict__ wo,
    const float* __restrict__ fc_w, const float* __restrict__ proj_w,
    const float* __restrict__ out_w, __hip_bfloat16* __restrict__ Wt_all) {
    int bid = blockIdx.x;
    const float* W;
    __hip_bfloat16* Wt;
    int K, N, tn, tk;
    if (bid < 6 * 6912) {
        int l = bid / 6912, r = bid % 6912;
        __hip_bfloat16* base = Wt_all + (size_t)l * PL;
        if (r < 1728) {
            int which = r / 576, idx = r % 576;
            W = (which == 0 ? wq : (which == 1 ? wk : wv)) + (size_t)l * DD * DD;
            Wt = base + (size_t)which * DD * DD;
            K = DD; N = DD; tn = idx % 24; tk = idx / 24;
        } else if (r < 2304) {
            int idx = r - 1728;
            W = wo + (size_t)l * DD * DD;
            Wt = base + OFF_WO;
            K = DD; N = DD; tn = idx % 24; tk = idx / 24;
        } else if (r < 4608) {
            int idx = r - 2304;
            W = fc_w + (size_t)l * DD * FF;
            Wt = base + OFF_FC;
            K = DD; N = FF; tn = idx % 96; tk = idx / 96;
        } else {
            int idx = r - 4608;
            W = proj_w + (size_t)l * FF * DD;
            Wt = base + OFF_PROJ;
            K = FF; N = DD; tn = idx % 24; tk = idx / 24;
        }
    } else {
        int idx = bid - 6 * 6912;
        W = out_w;
        Wt = Wt_all + (size_t)6 * PL;
        K = DD; N = VV; tn = idx % 1571; tk = idx / 1571;
    }
    __shared__ float t[32][33];
    int bn = tn * 32, bk = tk * 32;
    int tx = threadIdx.x & 31, ty = threadIdx.x >> 5;
    for (int r = ty; r < 32; r += 8)
        t[r][tx] = (bn + tx < N) ? W[(size_t)(bk + r) * N + bn + tx] : 0.0f;
    __syncthreads();
    for (int r = ty; r < 32; r += 8) {
        int n = bn + r;
        if (n < N) Wt[(size_t)n * K + bk + tx] = __float2bfloat16(t[tx][r]);
    }
}

// LDS rows are 64B (32 bf16); 16B slots XOR-swizzled by ((row>>1)&3).
#define LDSOFF(row, ks) (((row) * 64) + ((((ks) ^ (((row) >> 1) & 3))) << 4))
// swizzled byte offset within a [rows][128B] LDS tile (flash attn)
#define SWZ128(row, byteoff) \
    ((row) * 128 + (((((byteoff) >> 4) ^ ((row) & 7)) & 7) << 4) + ((byteoff) & 15))

// XCD-grouped, M-fastest tile remap. nblk must be launched 1-D.
__device__ __forceinline__ void tile_remap(int mtiles, int BM, int BN, int& bm, int& bn) {
    const int nblk = gridDim.x;
    int hw = blockIdx.x, j = hw;
    if ((nblk & 7) == 0) j = (hw & 7) * (nblk >> 3) + (hw >> 3);
    bm = (j % mtiles) * BM;
    bn = (j / mtiles) * BN;
}

// ============ 256x256 double-buffered GEMM (logits-class) ============
__global__ __launch_bounds__(512) void gemm256_kernel(
    const __hip_bfloat16* __restrict__ A, const __hip_bfloat16* __restrict__ Wt,
    const float* __restrict__ bias, float* __restrict__ Cf,
    __hip_bfloat16* __restrict__ Cb, int M, int N, int K, int do_gelu, int mtiles) {
    __shared__ __align__(16) char lds[65536];
    const int tid = threadIdx.x;
    const int lane = tid & 63;
    const int w = tid >> 6;                // 0..7
    const int wr = w >> 2, wc = w & 3;     // wave grid 2(M) x 4(N)
    const int r16 = lane & 15, kg = lane >> 4;
    int bm, bn;
    tile_remap(mtiles, 256, 256, bm, bn);

    auto STAGE = [&](int T) {
        char* lb = lds + (T & 1) * 32768;
        int k0 = T * 32;
#pragma unroll
        for (int u = 0; u < 2; ++u) {
            int cb = w * 128 + u * 64;     // wave-uniform chunk base
            int c = cb + lane;
            int row = c >> 2;              // 4x16B chunks per 64B row
            int sc = ((c & 3) ^ ((row >> 1) & 3)) * 8;   // inverse-swizzled k-slot
            gload16(A + (size_t)(bm + row) * K + k0 + sc, lb + cb * 16);
            gload16(Wt + (size_t)(bn + row) * K + k0 + sc, lb + 16384 + cb * 16);
        }
    };

    f32x4 acc[8][4];
    const f32x4 zf = {0.0f, 0.0f, 0.0f, 0.0f};
#pragma unroll
    for (int i = 0; i < 8; ++i)
#pragma unroll
        for (int j = 0; j < 4; ++j) acc[i][j] = zf;

    unsigned aoff[8], boff[4];
#pragma unroll
    for (int i = 0; i < 8; ++i) aoff[i] = LDSOFF(wr * 128 + i * 16 + r16, kg);
#pragma unroll
    for (int j = 0; j < 4; ++j) boff[j] = 16384 + LDSOFF(wc * 64 + j * 16 + r16, kg);
    const unsigned lbase = lds_off(lds);

    STAGE(0); STAGE(1);                    // 8 loads/wave in flight
    const int NT = K >> 5;
    for (int t = 0; t < NT; ++t) {
        if (t < NT - 1) asm volatile("s_waitcnt vmcnt(4)" ::: "memory");
        else            asm volatile("s_waitcnt vmcnt(0)" ::: "memory");
        __builtin_amdgcn_s_barrier();      // tile t globally complete
        __builtin_amdgcn_sched_barrier(0);
        unsigned ab = lbase + (unsigned)(t & 1) * 32768u;
        short8v af[8], bf[4];
#pragma unroll
        for (int i = 0; i < 8; ++i) af[i] = ds_read128(ab + aoff[i]);
#pragma unroll
        for (int j = 0; j < 4; ++j) bf[j] = ds_read128(ab + boff[j]);
        asm volatile("s_waitcnt lgkmcnt(0)" ::: "memory");
        __builtin_amdgcn_sched_barrier(0); // rule 18: pin everything below the wait
        __builtin_amdgcn_s_barrier();      // all waves done READING buf[t&1]
        if (t + 2 < NT) STAGE(t + 2);      // overwrite buf[t&1] for tile t+2
        __builtin_amdgcn_s_setprio(1);
#pragma unroll
        for (int i = 0; i < 8; ++i)
#pragma unroll
            for (int j = 0; j < 4; ++j)
                acc[i][j] = __builtin_amdgcn_mfma_f32_16x16x32_bf16(
                    af[i], bf[j], acc[i][j], 0, 0, 0);
        __builtin_amdgcn_s_setprio(0);
    }

    const int rg = lane >> 4;
#pragma unroll
    for (int i = 0; i < 8; ++i)
#pragma unroll
        for (int j = 0; j < 4; ++j) {
            int col = bn + wc * 64 + j * 16 + r16;
            if (col < N) {
#pragma unroll
                for (int r = 0; r < 4; ++r) {
                    int row = bm + wr * 128 + i * 16 + rg * 4 + r;
                    float v = acc[i][j][r];
                    if (bias) v += bias[col];
                    if (do_gelu) v = gelu_f(v);
                    if (Cf) Cf[(size_t)row * N + col] = v;
                    else Cb[(size_t)row * N + col] = __float2bfloat16(v);
                }
            }
        }
}

// ============ 128x128 deep-pipelined GEMM (4-buffer, 2 blocks/CU) ============
__global__ __launch_bounds__(256) void gemm128_kernel(
    const __hip_bfloat16* __restrict__ A, const __hip_bfloat16* __restrict__ Wt,
    const float* __restrict__ bias, float* __restrict__ Cf,
    __hip_bfloat16* __restrict__ Cb, int M, int N, int K, int do_gelu, int mtiles) {
    __shared__ __align__(16) char lds[65536];
    const int tid = threadIdx.x;
    const int lane = tid & 63;
    const int w = tid >> 6;                // 0..3
    const int wr = w >> 1, wc = w & 1;     // wave grid 2x2
    const int r16 = lane & 15, kg = lane >> 4;
    int bm, bn;
    tile_remap(mtiles, 128, 128, bm, bn);

    auto STAGE = [&](int T) {
        char* lb = lds + (T & 3) * 16384;
        int k0 = T * 32;
#pragma unroll
        for (int u = 0; u < 2; ++u) {
            int cb = w * 128 + u * 64;     // wave-uniform chunk base (512 chunks/tile)
            int c = cb + lane;
            int row = c >> 2;
            int sc = ((c & 3) ^ ((row >> 1) & 3)) * 8;
            gload16(A + (size_t)(bm + row) * K + k0 + sc, lb + cb * 16);
            gload16(Wt + (size_t)(bn + row) * K + k0 + sc, lb + 8192 + cb * 16);
        }
    };

    f32x4 acc[4][4];
    const f32x4 zf = {0.0f, 0.0f, 0.0f, 0.0f};
#pragma unroll
    for (int i = 0; i < 4; ++i)
#pragma unroll
        for (int j = 0; j < 4; ++j) acc[i][j] = zf;

    unsigned aoff[4], boff[4];
#pragma unroll
    for (int i = 0; i < 4; ++i) aoff[i] = LDSOFF(wr * 64 + i * 16 + r16, kg);
#pragma unroll
    for (int j = 0; j < 4; ++j) boff[j] = 8192 + LDSOFF(wc * 64 + j * 16 + r16, kg);
    const unsigned lbase = lds_off(lds);

    STAGE(0); STAGE(1); STAGE(2);
    const int NT = K >> 5;
    for (int t = 0; t < NT; ++t) {
        if (t < NT - 2)       asm volatile("s_waitcnt vmcnt(8)" ::: "memory");
        else if (t == NT - 2) asm volatile("s_waitcnt vmcnt(4)" ::: "memory");
        else                  asm volatile("s_waitcnt vmcnt(0)" ::: "memory");
        __builtin_amdgcn_s_barrier();
        __builtin_amdgcn_sched_barrier(0);
        if (t + 3 < NT) STAGE(t + 3);
        unsigned ab = lbase + (unsigned)(t & 3) * 16384u;
        short8v af[4], bf[4];
#pragma unroll
        for (int i = 0; i < 4; ++i) af[i] = ds_read128(ab + aoff[i]);
#pragma unroll
        for (int j = 0; j < 4; ++j) bf[j] = ds_read128(ab + boff[j]);
        asm volatile("s_waitcnt lgkmcnt(0)" ::: "memory");
        __builtin_amdgcn_sched_barrier(0);
        __builtin_amdgcn_s_setprio(1);
#pragma unroll
        for (int i = 0; i < 4; ++i)
#pragma unroll
            for (int j = 0; j < 4; ++j)
                acc[i][j] = __builtin_amdgcn_mfma_f32_16x16x32_bf16(
                    af[i], bf[j], acc[i][j], 0, 0, 0);
        __builtin_amdgcn_s_setprio(0);
    }

    const int rg = lane >> 4;
#pragma unroll
    for (int i = 0; i < 4; ++i)
#pragma unroll
        for (int j = 0; j < 4; ++j) {
            int col = bn + wc * 64 + j * 16 + r16;
#pragma unroll
            for (int r = 0; r < 4; ++r) {
                int row = bm + wr * 64 + i * 16 + rg * 4 + r;
                float v = acc[i][j][r];
                if (bias) v += bias[col];
                if (do_gelu) v = gelu_f(v);
                if (Cf) Cf[(size_t)row * N + col] = v;
                else Cb[(size_t)row * N + col] = __float2bfloat16(v);
            }
        }
}

// ============ 64x64 deep-pipelined GEMM (wo/proj-class, full-grid fill) ============
__global__ __launch_bounds__(256) void gemm64_kernel(
    const __hip_bfloat16* __restrict__ A, const __hip_bfloat16* __restrict__ Wt,
    const float* __restrict__ bias, const float* __restrict__ residual,
    float* __restrict__ Cf, __hip_bfloat16* __restrict__ Cb,
    int M, int N, int K, int do_gelu, int mtiles) {
    __shared__ __align__(16) char lds[32768];
    const int tid = threadIdx.x;
    const int lane = tid & 63;
    const int w = tid >> 6;                // 0..3
    const int wr = w >> 1, wc = w & 1;
    const int r16 = lane & 15, kg = lane >> 4;
    int bm, bn;
    tile_remap(mtiles, 64, 64, bm, bn);

    auto STAGE = [&](int T) {
        char* lb = lds + (T & 3) * 8192;
        int k0 = T * 32;
        int cb = w * 64;                   // 256 chunks/tile, 1 per thread
        int c = cb + lane;
        int row = c >> 2;
        int sc = ((c & 3) ^ ((row >> 1) & 3)) * 8;
        gload16(A + (size_t)(bm + row) * K + k0 + sc, lb + cb * 16);
        gload16(Wt + (size_t)(bn + row) * K + k0 + sc, lb + 4096 + cb * 16);
    };

    f32x4 acc[2][2];
    const f32x4 zf = {0.0f, 0.0f, 0.0f, 0.0f};
#pragma unroll
    for (int i = 0; i < 2; ++i)
#pragma unroll
        for (int j = 0; j < 2; ++j) acc[i][j] = zf;

    unsigned aoff[2], boff[2];
#pragma unroll
    for (int i = 0; i < 2; ++i) aoff[i] = LDSOFF(wr * 32 + i * 16 + r16, kg);
#pragma unroll
    for (int j = 0; j < 2; ++j) boff[j] = 4096 + LDSOFF(wc * 32 + j * 16 + r16, kg);
    const unsigned lbase = lds_off(lds);

    STAGE(0); STAGE(1); STAGE(2);          // 6 loads/wave in flight
    const int NT = K >> 5;
    for (int t = 0; t < NT; ++t) {
        if (t < NT - 2)       asm volatile("s_waitcnt vmcnt(4)" ::: "memory");
        else if (t == NT - 2) asm volatile("s_waitcnt vmcnt(2)" ::: "memory");
        else                  asm volatile("s_waitcnt vmcnt(0)" ::: "memory");
        __builtin_amdgcn_s_barrier();
        __builtin_amdgcn_sched_barrier(0);
        if (t + 3 < NT) STAGE(t + 3);
        unsigned ab = lbase + (unsigned)(t & 3) * 8192u;
        short8v af[2], bf[2];
#pragma unroll
        for (int i = 0; i < 2; ++i) af[i] = ds_read128(ab + aoff[i]);
#pragma unroll
        for (int j = 0; j < 2; ++j) bf[j] = ds_read128(ab + boff[j]);
        asm volatile("s_waitcnt lgkmcnt(0)" ::: "memory");
        __builtin_amdgcn_sched_barrier(0);
        __builtin_amdgcn_s_setprio(1);
#pragma unroll
        for (int i = 0; i < 2; ++i)
#pragma unroll
            for (int j = 0; j < 2; ++j)
                acc[i][j] = __builtin_amdgcn_mfma_f32_16x16x32_bf16(
                    af[i], bf[j], acc[i][j], 0, 0, 0);
        __builtin_amdgcn_s_setprio(0);
    }

    const int rg = lane >> 4;
#pragma unroll
    for (int i = 0; i < 2; ++i)
#pragma unroll
        for (int j = 0; j < 2; ++j) {
            int col = bn + wc * 32 + j * 16 + r16;
#pragma unroll
            for (int r = 0; r < 4; ++r) {
                int row = bm + wr * 32 + i * 16 + rg * 4 + r;
                float v = acc[i][j][r];
                if (bias) v += bias[col];
                if (do_gelu) v = gelu_f(v);
                size_t o = (size_t)row * N + col;
                if (residual) v += residual[o];
                if (Cf) Cf[o] = v;
                else Cb[o] = __float2bfloat16(v);
            }
        }
}

// ============ QKV deep-pipelined 128x128 GEMM with head-split epilogue ============
__global__ __launch_bounds__(256) void qkv_gemm_kernel(
    const __hip_bfloat16* __restrict__ A, const __hip_bfloat16* __restrict__ Wt,
    __hip_bfloat16* __restrict__ qh, __hip_bfloat16* __restrict__ kh,
    __hip_bfloat16* __restrict__ vt) {
    constexpr int K = DD;
    __shared__ __align__(16) char lds[65536];
    const int tid = threadIdx.x;
    const int lane = tid & 63;
    const int w = tid >> 6;
    const int wr = w >> 1, wc = w & 1;
    const int r16 = lane & 15, kg = lane >> 4;
    int bm, bn;
    tile_remap(16, 128, 128, bm, bn);

    auto STAGE = [&](int T) {
        char* lb = lds + (T & 3) * 16384;
        int k0 = T * 32;
#pragma unroll
        for (int u = 0; u < 2; ++u) {
            int cb = w * 128 + u * 64;
            int c = cb + lane;
            int row = c >> 2;
            int sc = ((c & 3) ^ ((row >> 1) & 3)) * 8;
            gload16(A + (size_t)(bm + row) * K + k0 + sc, lb + cb * 16);
            gload16(Wt + (size_t)(bn + row) * K + k0 + sc, lb + 8192 + cb * 16);
        }
    };

    f32x4 acc[4][4];
    const f32x4 zf = {0.0f, 0.0f, 0.0f, 0.0f};
#pragma unroll
    for (int i = 0; i < 4; ++i)
#pragma unroll
        for (int j = 0; j < 4; ++j) acc[i][j] = zf;

    unsigned aoff[4], boff[4];
#pragma unroll
    for (int i = 0; i < 4; ++i) aoff[i] = LDSOFF(wr * 64 + i * 16 + r16, kg);
#pragma unroll
    for (int j = 0; j < 4; ++j) boff[j] = 8192 + LDSOFF(wc * 64 + j * 16 + r16, kg);
    const unsigned lbase = lds_off(lds);

    STAGE(0); STAGE(1); STAGE(2);
    const int NT = K >> 5;                 // 24
    for (int t = 0; t < NT; ++t) {
        if (t < NT - 2)       asm volatile("s_waitcnt vmcnt(8)" ::: "memory");
        else if (t == NT - 2) asm volatile("s_waitcnt vmcnt(4)" ::: "memory");
        else                  asm volatile("s_waitcnt vmcnt(0)" ::: "memory");
        __builtin_amdgcn_s_barrier();
        __builtin_amdgcn_sched_barrier(0);
        if (t + 3 < NT) STAGE(t + 3);
        unsigned ab = lbase + (unsigned)(t & 3) * 16384u;
        short8v af[4], bf[4];
#pragma unroll
        for (int i = 0; i < 4; ++i) af[i] = ds_read128(ab + aoff[i]);
#pragma unroll
        for (int j = 0; j < 4; ++j) bf[j] = ds_read128(ab + boff[j]);
        asm volatile("s_waitcnt lgkmcnt(0)" ::: "memory");
        __builtin_amdgcn_sched_barrier(0);
        __builtin_amdgcn_s_setprio(1);
#pragma unroll
        for (int i = 0; i < 4; ++i)
#pragma unroll
            for (int j = 0; j < 4; ++j)
                acc[i][j] = __builtin_amdgcn_mfma_f32_16x16x32_bf16(
                    af[i], bf[j], acc[i][j], 0, 0, 0);
        __builtin_amdgcn_s_setprio(0);
    }

#pragma unroll
    for (int i = 0; i < 4; ++i) {
#pragma unroll
        for (int j = 0; j < 4; ++j) {
            int col = bn + wc * 64 + j * 16 + r16;
#pragma unroll
            for (int r = 0; r < 4; ++r) {
                int row = bm + wr * 64 + i * 16 + kg * 4 + r;   // b*S + s
                int b = row >> 10, s = row & (SS - 1);
                float v = acc[i][j][r];
                if (col < DD) {
                    int h = col >> 6, d = col & 63;
                    qh[((size_t)(b * HH + h) * SS + s) * DKK + d] =
                        __float2bfloat16(v * 0.125f);       // fold 1/sqrt(64)
                } else if (col < 2 * DD) {
                    int c = col - DD, h = c >> 6, d = c & 63;
                    kh[((size_t)(b * HH + h) * SS + s) * DKK + d] = __float2bfloat16(v);
                } else {
                    int c = col - 2 * DD, h = c >> 6, d = c & 63;
                    vt[((size_t)(b * HH + h) * DKK + d) * SS + s] = __float2bfloat16(v);
                }
            }
        }
    }
}

// ---------------- flash attention (T14 + dbuf K/V: ONE barrier per KV-tile) --------
__global__ __launch_bounds__(256) void flash_attn_kernel(
    const __hip_bfloat16* __restrict__ qh, const __hip_bfloat16* __restrict__ kh,
    const __hip_bfloat16* __restrict__ vt, __hip_bfloat16* __restrict__ ctx) {
    __shared__ __align__(16) char Ks[2][KVBLK * 128];
    __shared__ __align__(16) char Vs[2][DKK * 128];
    __shared__ __align__(16) char Ps[4][16 * 128];

    const int bh = blockIdx.x;
    const int qt = (gridDim.y - 1) - blockIdx.y;
    const int q0 = qt * QBLK;
    const int b = bh / HH;
    const int h = bh - b * HH;
    const int tid = threadIdx.x;
    const int lane = tid & 63;
    const int w = tid >> 6;
    const int r16 = lane & 15;
    const int kg = lane >> 4;
    char* Pw = Ps[w];

    const size_t qbase = ((size_t)bh * SS + q0 + w * 16 + r16) * DKK;
    short8v qf0 = *(const short8v*)(qh + qbase + kg * 8);
    short8v qf1 = *(const short8v*)(qh + qbase + 32 + kg * 8);

    const __hip_bfloat16* kbase = kh + (size_t)bh * SS * DKK;
    const __hip_bfloat16* vbase = vt + (size_t)bh * DKK * SS;
    // this thread's staging coordinates (2 chunks: c and c+256)
    const int row0 = tid >> 3, slot0 = tid & 7;
    const int row1 = (tid + 256) >> 3, slot1 = tid & 7;   // (tid+256)&7 == tid&7

    int4v kreg0, kreg1, vreg0, vreg1;
    {   // prologue: load tile 0 into regs
        kreg0 = *(const int4v*)(kbase + (size_t)row0 * DKK + slot0 * 8);
        kreg1 = *(const int4v*)(kbase + (size_t)row1 * DKK + slot1 * 8);
        vreg0 = *(const int4v*)(vbase + (size_t)row0 * SS + slot0 * 8);
        vreg1 = *(const int4v*)(vbase + (size_t)row1 * SS + slot1 * 8);
    }

    f32x4 acc_o[4];
    const f32x4 zf = {0.0f, 0.0f, 0.0f, 0.0f};
    float m[4], l[4];
#pragma unroll
    for (int j = 0; j < 4; ++j) acc_o[j] = zf;
#pragma unroll
    for (int r = 0; r < 4; ++r) { m[r] = -1e30f; l[r] = 0.0f; }

    const int nt = qt + 1;
    for (int t = 0; t < nt; ++t) {
        // write tile t into buf[t&1]; any lagging wave computing t-1 reads buf[(t-1)&1]
        char* Kb = Ks[t & 1];
        char* Vb = Vs[t & 1];
        *(int4v*)(Kb + SWZ128(row0, slot0 * 16)) = kreg0;
        *(int4v*)(Kb + SWZ128(row1, slot1 * 16)) = kreg1;
        *(int4v*)(Vb + SWZ128(row0, slot0 * 16)) = vreg0;
        *(int4v*)(Vb + SWZ128(row1, slot1 * 16)) = vreg1;
        __syncthreads();   // single barrier: tile t visible to all waves

        if (t + 1 < nt) {  // T14: issue next-tile loads; latency hides under compute
            const __hip_bfloat16* kp = kbase + (size_t)(t + 1) * KVBLK * DKK;
            const __hip_bfloat16* vp = vbase + (t + 1) * KVBLK;
            kreg0 = *(const int4v*)(kp + (size_t)row0 * DKK + slot0 * 8);
            kreg1 = *(const int4v*)(kp + (size_t)row1 * DKK + slot1 * 8);
            vreg0 = *(const int4v*)(vp + (size_t)row0 * SS + slot0 * 8);
            vreg1 = *(const int4v*)(vp + (size_t)row1 * SS + slot1 * 8);
        }

        f32x4 s[4];
#pragma unroll
        for (int j = 0; j < 4; ++j) s[j] = zf;
        __builtin_amdgcn_s_setprio(1);
#pragma unroll
        for (int j = 0; j < 4; ++j) {
            short8v k0f = *(const short8v*)(Kb + SWZ128(j * 16 + r16, kg * 16));
            short8v k1f = *(const short8v*)(Kb + SWZ128(j * 16 + r16, 64 + kg * 16));
            s[j] = __builtin_amdgcn_mfma_f32_16x16x32_bf16(qf0, k0f, s[j], 0, 0, 0);
            s[j] = __builtin_amdgcn_mfma_f32_16x16x32_bf16(qf1, k1f, s[j], 0, 0, 0);
        }
        __builtin_amdgcn_s_setprio(0);

        if (t == qt) {
#pragma unroll
            for (int j = 0; j < 4; ++j)
#pragma unroll
                for (int r = 0; r < 4; ++r)
                    if (j * 16 + r16 > w * 16 + kg * 4 + r) s[j][r] = -1e30f;
        }

        float alpha[4], rsum[4];
#pragma unroll
        for (int r = 0; r < 4; ++r) {
            float v = fmaxf(fmaxf(s[0][r], s[1][r]), fmaxf(s[2][r], s[3][r]));
#pragma unroll
            for (int d2 = 1; d2 < 16; d2 <<= 1)
                v = fmaxf(v, __shfl_xor(v, d2));
            float mnew = fmaxf(m[r], v);
            alpha[r] = __expf(m[r] - mnew);
            m[r] = mnew;
            rsum[r] = 0.0f;
        }
#pragma unroll
        for (int j = 0; j < 4; ++j)
#pragma unroll
            for (int r = 0; r < 4; ++r) {
                float p = __expf(s[j][r] - m[r]);
                rsum[r] += p;
                *(__hip_bfloat16*)(Pw + SWZ128(kg * 4 + r, (j * 16 + r16) * 2)) =
                    __float2bfloat16(p);
            }
#pragma unroll
        for (int r = 0; r < 4; ++r) {
#pragma unroll
            for (int d2 = 1; d2 < 16; d2 <<= 1)
                rsum[r] += __shfl_xor(rsum[r], d2);
            l[r] = l[r] * alpha[r] + rsum[r];
        }
#pragma unroll
        for (int j = 0; j < 4; ++j)
#pragma unroll
            for (int r = 0; r < 4; ++r) acc_o[j][r] *= alpha[r];

        short8v pa0 = *(const short8v*)(Pw + SWZ128(r16, kg * 16));
        short8v pa1 = *(const short8v*)(Pw + SWZ128(r16, 64 + kg * 16));
        __builtin_amdgcn_s_setprio(1);
#pragma unroll
        for (int j = 0; j < 4; ++j) {
            short8v v0f = *(const short8v*)(Vb + SWZ128(j * 16 + r16, kg * 16));
            short8v v1f = *(const short8v*)(Vb + SWZ128(j * 16 + r16, 64 + kg * 16));
            acc_o[j] = __builtin_amdgcn_mfma_f32_16x16x32_bf16(pa0, v0f, acc_o[j], 0, 0, 0);
            acc_o[j] = __builtin_amdgcn_mfma_f32_16x16x32_bf16(pa1, v1f, acc_o[j], 0, 0, 0);
        }
        __builtin_amdgcn_s_setprio(0);
    }

#pragma unroll
    for (int r = 0; r < 4; ++r) {
        float inv = 1.0f / l[r];
        int row = q0 + w * 16 + kg * 4 + r;
        __hip_bfloat16* cp = ctx + ((size_t)(b * SS) + row) * DD + h * DKK;
#pragma unroll
        for (int j = 0; j < 4; ++j)
            cp[j * 16 + r16] = __float2bfloat16(acc_o[j][r] * inv);
    }
}

// ---------------- fp32 fallback GEMM / attention ----------------
__global__ __launch_bounds__(256) void gemm_kernel(
    const float* __restrict__ A, const float* __restrict__ W,
    const float* __restrict__ bias, const float* __restrict__ residual,
    float* __restrict__ C, int M, int N, int K, int do_gelu) {
    __shared__ float As[16][64];
    __shared__ float Ws[16][68];
    int tid = threadIdx.x;
    int bn = blockIdx.x * 64, bm = blockIdx.y * 64;
    int tx = tid & 15, ty = tid >> 4;
    int ar = tid >> 2, ak = (tid & 3) << 2;
    int wr = tid >> 4, wc = (tid & 15) << 2;
    bool n_vec = ((N & 3) == 0);
    float acc[4][4] = {};
    for (int k0 = 0; k0 < K; k0 += 16) {
        float4 av = *(const float4*)&A[(size_t)(bm + ar) * K + (k0 + ak)];
        As[ak + 0][ar] = av.x; As[ak + 1][ar] = av.y;
        As[ak + 2][ar] = av.z; As[ak + 3][ar] = av.w;
        int gn = bn + wc;
        const float* wp = &W[(size_t)(k0 + wr) * N + gn];
        float w0, w1, w2, w3;
        if (n_vec && gn + 3 < N) {
            float4 wv4 = *(const float4*)wp;
            w0 = wv4.x; w1 = wv4.y; w2 = wv4.z; w3 = wv4.w;
        } else {
            w0 = (gn + 0 < N) ? wp[0] : 0.0f;
            w1 = (gn + 1 < N) ? wp[1] : 0.0f;
            w2 = (gn + 2 < N) ? wp[2] : 0.0f;
            w3 = (gn + 3 < N) ? wp[3] : 0.0f;
        }
        Ws[wr][wc + 0] = w0; Ws[wr][wc + 1] = w1;
        Ws[wr][wc + 2] = w2; Ws[wr][wc + 3] = w3;
        __syncthreads();
#pragma unroll
        for (int kk = 0; kk < 16; ++kk) {
            float a[4], w[4];
#pragma unroll
            for (int i = 0; i < 4; ++i) a[i] = As[kk][ty * 4 + i];
#pragma unroll
            for (int j = 0; j < 4; ++j) w[j] = Ws[kk][tx * 4 + j];
#pragma unroll
            for (int i = 0; i < 4; ++i)
#pragma unroll
                for (int j = 0; j < 4; ++j)
                    acc[i][j] = fmaf(a[i], w[j], acc[i][j]);
        }
        __syncthreads();
    }
#pragma unroll
    for (int i = 0; i < 4; ++i) {
        int row = bm + ty * 4 + i;
#pragma unroll
        for (int j = 0; j < 4; ++j) {
            int col = bn + tx * 4 + j;
            if (col < N) {
                float val = acc[i][j];
                if (bias) val += bias[col];
                if (do_gelu) val = gelu_f(val);
                if (residual) val += residual[(size_t)row * N + col];
                C[(size_t)row * N + col] = val;
            }
        }
    }
}

__global__ __launch_bounds__(256) void attn_kernel(
    const float* __restrict__ q, const float* __restrict__ k,
    const float* __restrict__ v, float* __restrict__ ctx) {
    int bid = blockIdx.x;
    int qi = bid & (SS - 1);
    int bh = bid >> 10;
    int h = bh % HH;
    int b = bh / HH;
    int tid = threadIdx.x;
    __shared__ float qs[DKK];
    __shared__ float p[SS];
    __shared__ float red[256];
    __shared__ float ctx_red[4][DKK];
    const float* qrow = q + ((size_t)(b * SS + qi)) * DD + h * DKK;
    if (tid < DKK) qs[tid] = qrow[tid];
    __syncthreads();
    int nk = qi + 1;
    const float scale = 0.125f;
    for (int ki = tid; ki < nk; ki += 256) {
        const float* krow = k + ((size_t)(b * SS + ki)) * DD + h * DKK;
        float dot = 0.0f;
#pragma unroll
        for (int d = 0; d < DKK; d += 4) {
            float4 kv = *(const float4*)&krow[d];
            dot += qs[d] * kv.x + qs[d + 1] * kv.y + qs[d + 2] * kv.z + qs[d + 3] * kv.w;
        }
        p[ki] = dot * scale;
    }
    __syncthreads();
    float lmax = -1e30f;
    for (int ki = tid; ki < nk; ki += 256) lmax = fmaxf(lmax, p[ki]);
    red[tid] = lmax;
    __syncthreads();
    for (int s2 = 128; s2 > 0; s2 >>= 1) {
        if (tid < s2) red[tid] = fmaxf(red[tid], red[tid + s2]);
        __syncthreads();
    }
    float mm = red[0];
    __syncthreads();
    float lsum = 0.0f;
    for (int ki = tid; ki < nk; ki += 256) {
        float e = __expf(p[ki] - mm);
        p[ki] = e;
        lsum += e;
    }
    red[tid] = lsum;
    __syncthreads();
    for (int s2 = 128; s2 > 0; s2 >>= 1) {
        if (tid < s2) red[tid] += red[tid + s2];
        __syncthreads();
    }
    float inv = 1.0f / red[0];
    int d = tid & 63;
    int chunk = tid >> 6;
    float accd = 0.0f;
    for (int ki = chunk; ki < nk; ki += 4)
        accd += p[ki] * v[((size_t)(b * SS + ki)) * DD + h * DKK + d];
    ctx_red[chunk][d] = accd;
    __syncthreads();
    if (tid < DKK) {
        float sum = (ctx_red[0][tid] + ctx_red[1][tid]) + (ctx_red[2][tid] + ctx_red[3][tid]);
        ctx[((size_t)(b * SS + qi)) * DD + h * DKK + tid] = sum * inv;
    }
}

// ---------------- host-side orchestration ----------------
extern "C" void kernel_launch(void* const* d_in, const int* in_sizes, int n_in,
                              void* d_out, int out_size, void* d_ws, size_t ws_size,
                              hipStream_t stream) {
    const int*   ids    = (const int*)  d_in[0];
    const float* tok    = (const float*)d_in[1];
    const float* pos    = (const float*)d_in[2];
    const float* wq     = (const float*)d_in[3];
    const float* wk     = (const float*)d_in[4];
    const float* wv     = (const float*)d_in[5];
    const float* wo     = (const float*)d_in[6];
    const float* bo     = (const float*)d_in[7];
    const float* fc_w   = (const float*)d_in[8];
    const float* fc_b   = (const float*)d_in[9];
    const float* proj_w = (const float*)d_in[10];
    const float* proj_b = (const float*)d_in[11];
    const float* ln1_g  = (const float*)d_in[12];
    const float* ln1_b  = (const float*)d_in[13];
    const float* ln2_g  = (const float*)d_in[14];
    const float* ln2_b  = (const float*)d_in[15];
    const float* lnf_g  = (const float*)d_in[16];
    const float* lnf_b  = (const float*)d_in[17];
    const float* out_w  = (const float*)d_in[18];
    float* out = (float*)d_out;

    dim3 blk(256);

    const size_t SZ_X    = (size_t)NROWS * DD * 4;
    const size_t SZ_XN   = (size_t)NROWS * DD * 2;
    const size_t SZ_HD   = (size_t)BB * HH * SS * DKK * 2;
    const size_t SZ_CTX  = (size_t)NROWS * DD * 2;
    const size_t SZ_H    = (size_t)NROWS * FF * 2;
    const size_t SZ_WT1  = (size_t)VPAD * DD * 2;                      // shared (mid)
    const size_t SZ_WTA  = ((size_t)6 * PL + (size_t)VPAD * DD) * 2;   // all (big)
    const size_t ACT     = SZ_X + SZ_XN + 3 * SZ_HD + SZ_CTX + SZ_H;
    const size_t NEED_MID = ACT + SZ_WT1;
    const size_t NEED_BIG = ACT + SZ_WTA;

    if (ws_size >= NEED_MID) {
        const bool big = (ws_size >= NEED_BIG);
        char* p = (char*)d_ws;
        float*          x    = (float*)p;          p += SZ_X;
        __hip_bfloat16* xn   = (__hip_bfloat16*)p; p += SZ_XN;
        __hip_bfloat16* qhb  = (__hip_bfloat16*)p; p += SZ_HD;
        __hip_bfloat16* khb  = (__hip_bfloat16*)p; p += SZ_HD;
        __hip_bfloat16* vtb  = (__hip_bfloat16*)p; p += SZ_HD;
        __hip_bfloat16* ctx  = (__hip_bfloat16*)p; p += SZ_CTX;
        __hip_bfloat16* hbuf = (__hip_bfloat16*)p; p += SZ_H;
        __hip_bfloat16* Wt   = (__hip_bfloat16*)p;

        dim3 tD(DD / 32, DD / 32);
        dim3 tF(FF / 32, DD / 32);
        dim3 tP(DD / 32, FF / 32);
        dim3 tV((VV + 31) / 32, DD / 32);

        const int nQKV = (QKVN / 128) * (NROWS / 128);       // 288 (128^2 deep-pipe)
        const int nWO  = (DD / 64) * (NROWS / 64);           // 384 (64^2 deep-pipe)
        const int nFC  = (FF / 128) * (NROWS / 128);         // 384 (128^2 deep-pipe)
        const int nV   = (VPAD / 256) * (NROWS / 256);       // 1576 (256^2 dbuf)
        dim3 gA(BB * HH, SS / QBLK);                         // 24 x 16

        if (big)
            transpose_all_kernel<<<6 * 6912 + 37704, blk, 0, stream>>>(
                wq, wk, wv, wo, fc_w, proj_w, out_w, Wt);

        embed_kernel<<<NROWS, blk, 0, stream>>>(ids, tok, pos, x);

        for (int l = 0; l < LL; ++l) {
            __hip_bfloat16* qkvWt = big ? Wt + (size_t)l * PL : Wt;
            __hip_bfloat16* woWt  = big ? Wt + (size_t)l * PL + OFF_WO : Wt;
            __hip_bfloat16* fcWt  = big ? Wt + (size_t)l * PL + OFF_FC : Wt;
            __hip_bfloat16* pjWt  = big ? Wt + (size_t)l * PL + OFF_PROJ : Wt;

            ln_bf16_kernel<<<NROWS, blk, 0, stream>>>(x, ln1_g + l * DD, ln1_b + l * DD, xn);
            if (!big) {
                transpose_cvt_kernel<<<tD, blk, 0, stream>>>(wq + (size_t)l * DD * DD, qkvWt, DD, DD);
                transpose_cvt_kernel<<<tD, blk, 0, stream>>>(wk + (size_t)l * DD * DD, qkvWt + (size_t)DD * DD, DD, DD);
                transpose_cvt_kernel<<<tD, blk, 0, stream>>>(wv + (size_t)l * DD * DD, qkvWt + (size_t)2 * DD * DD, DD, DD);
            }
            qkv_gemm_kernel<<<nQKV, blk, 0, stream>>>(xn, qkvWt, qhb, khb, vtb);
            flash_attn_kernel<<<gA, blk, 0, stream>>>(qhb, khb, vtb, ctx);
            if (!big)
                transpose_cvt_kernel<<<tD, blk, 0, stream>>>(wo + (size_t)l * DD * DD, woWt, DD, DD);
            gemm64_kernel<<<nWO, blk, 0, stream>>>(
                ctx, woWt, bo + l * DD, x, x, nullptr, NROWS, DD, DD, 0, NROWS / 64);
            ln_bf16_kernel<<<NROWS, blk, 0, stream>>>(x, ln2_g + l * DD, ln2_b + l * DD, xn);
            if (!big)
                transpose_cvt_kernel<<<tF, blk, 0, stream>>>(fc_w + (size_t)l * DD * FF, fcWt, DD, FF);
            gemm128_kernel<<<nFC, blk, 0, stream>>>(
                xn, fcWt, fc_b + l * FF, nullptr, hbuf, NROWS, FF, DD, 1, NROWS / 128);
            if (!big)
                transpose_cvt_kernel<<<tP, blk, 0, stream>>>(proj_w + (size_t)l * FF * DD, pjWt, FF, DD);
            gemm64_kernel<<<nWO, blk, 0, stream>>>(
                hbuf, pjWt, proj_b + l * DD, x, x, nullptr, NROWS, DD, FF, 0, NROWS / 64);
        }

        __hip_bfloat16* outWt = big ? Wt + (size_t)6 * PL : Wt;
        ln_bf16_kernel<<<NROWS, blk, 0, stream>>>(x, lnf_g, lnf_b, xn);
        if (!big)
            transpose_cvt_kernel<<<tV, blk, 0, stream>>>(out_w, outWt, DD, VV);
        gemm256_kernel<<<nV, 512, 0, stream>>>(
            xn, outWt, nullptr, out, nullptr, NROWS, VV, DD, 0, NROWS / 256);
        return;
    }

    // ---- fallback: proven fp32 path ----
    const size_t XSZ = (size_t)NROWS * DD;
    float* ws = (float*)d_ws;
    float* x  = ws;
    float* xn = x  + XSZ;
    float* qb = xn + XSZ;
    float* kb = qb + XSZ;
    float* vb = kb + XSZ;
    float* cb = vb + XSZ;
    float* hb = cb + XSZ;

    dim3 gD((DD + 63) / 64, NROWS / 64);
    dim3 gF((FF + 63) / 64, NROWS / 64);
    dim3 gV2((VV + 63) / 64, NROWS / 64);

    embed_kernel<<<NROWS, blk, 0, stream>>>(ids, tok, pos, x);
    for (int l = 0; l < LL; ++l) {
        const float* wq_l = wq + (size_t)l * DD * DD;
        const float* wk_l = wk + (size_t)l * DD * DD;
        const float* wv_l = wv + (size_t)l * DD * DD;
        const float* wo_l = wo + (size_t)l * DD * DD;
        const float* fc_w_l = fc_w + (size_t)l * DD * FF;
        const float* pj_w_l = proj_w + (size_t)l * FF * DD;
        ln_kernel<<<NROWS, blk, 0, stream>>>(x, ln1_g + l * DD, ln1_b + l * DD, xn);
        gemm_kernel<<<gD, blk, 0, stream>>>(xn, wq_l, nullptr, nullptr, qb, NROWS, DD, DD, 0);
        gemm_kernel<<<gD, blk, 0, stream>>>(xn, wk_l, nullptr, nullptr, kb, NROWS, DD, DD, 0);
        gemm_kernel<<<gD, blk, 0, stream>>>(xn, wv_l, nullptr, nullptr, vb, NROWS, DD, DD, 0);
        attn_kernel<<<BB * HH * SS, blk, 0, stream>>>(qb, kb, vb, cb);
        gemm_kernel<<<gD, blk, 0, stream>>>(cb, wo_l, bo + l * DD, x, x, NROWS, DD, DD, 0);
        ln_kernel<<<NROWS, blk, 0, stream>>>(x, ln2_g + l * DD, ln2_b + l * DD, xn);
        gemm_kernel<<<gF, blk, 0, stream>>>(xn, fc_w_l, fc_b + l * FF, nullptr, hb, NROWS, FF, DD, 1);
        gemm_kernel<<<gD, blk, 0, stream>>>(hb, pj_w_l, proj_b + l * DD, x, x, NROWS, DD, FF, 0);
    }
    ln_kernel<<<NROWS, blk, 0, stream>>>(x, lnf_g, lnf_b, xn);
    gemm_kernel<<<gV2, blk, 0, stream>>>(xn, out_w, nullptr, nullptr, out, NROWS, VV, DD, 0);
}